// Round 1
// baseline (251.964 us; speedup 1.0000x reference)
//
#include <hip/hip_runtime.h>
#include <hip/hip_bf16.h>
#include <cmath>
#include <stdint.h>

#define B_ 4
#define M_ 1024
#define N_ 2048
#define D_ 1024
#define H_ 16
#define DH_ 64
#define QT 128   // Q rows per block (4 waves x 32)
#define NT 64    // N tile
#define PITCH 72 // LDS row pitch in bf16 elems: 144B, 16B-aligned, 2-way banks (free)

typedef __bf16 bf16_t;
typedef __attribute__((ext_vector_type(8))) __bf16 bf16x8;
typedef __attribute__((ext_vector_type(4))) float f32x4;

static __device__ __forceinline__ float silu_f(float x) {
  return x / (1.0f + __expf(-x));
}

// ---- prep: K' = L2norm(silu(kv heads)) [bh][n][d], Vt = kv^T [bh][d][n], mask bits ----
__global__ __launch_bounds__(256) void prep_kernel(
    const float* __restrict__ kv, const int* __restrict__ kv_mask,
    bf16_t* __restrict__ kp, bf16_t* __restrict__ vt,
    unsigned long long* __restrict__ mb) {
  const int wave = threadIdx.x >> 6;
  const int lane = threadIdx.x & 63;
  const int row  = blockIdx.x * 4 + wave;   // 0..B*N-1
  const int b = row >> 11;                  // / N_
  const int n = row & (N_ - 1);
  const int hq = lane >> 4;                 // head quarter in this pass
  const int c  = lane & 15;                 // 4-float column group
  const float* src = kv + (size_t)row * D_;
  #pragma unroll
  for (int pass = 0; pass < 4; ++pass) {
    const int h = pass * 4 + hq;
    float4 v = *(const float4*)(src + h * DH_ + c * 4);
    float s0 = silu_f(v.x), s1 = silu_f(v.y), s2 = silu_f(v.z), s3 = silu_f(v.w);
    float ss = s0*s0 + s1*s1 + s2*s2 + s3*s3;
    ss += __shfl_xor(ss, 1); ss += __shfl_xor(ss, 2);
    ss += __shfl_xor(ss, 4); ss += __shfl_xor(ss, 8);
    const float inv = 1.0f / fmaxf(sqrtf(ss), 1e-6f);
    const size_t bh = (size_t)(b * H_ + h);
    union { bf16_t bs[4]; uint2 u; } pk;
    pk.bs[0] = (bf16_t)(s0 * inv); pk.bs[1] = (bf16_t)(s1 * inv);
    pk.bs[2] = (bf16_t)(s2 * inv); pk.bs[3] = (bf16_t)(s3 * inv);
    *(uint2*)(kp + (bh * N_ + n) * DH_ + c * 4) = pk.u;
    vt[(bh * DH_ + c*4 + 0) * N_ + n] = (bf16_t)v.x;
    vt[(bh * DH_ + c*4 + 1) * N_ + n] = (bf16_t)v.y;
    vt[(bh * DH_ + c*4 + 2) * N_ + n] = (bf16_t)v.z;
    vt[(bh * DH_ + c*4 + 3) * N_ + n] = (bf16_t)v.w;
  }
  // pack mask bits: word (b,t) bit i <-> kv_mask[b][t*64+i]
  if (blockIdx.x == 0 && threadIdx.x < B_ * (N_ / 64)) {
    const int t = threadIdx.x;
    const int b2 = t >> 5, tt = t & 31;
    unsigned long long m = 0ull;
    for (int i = 0; i < 64; ++i)
      if (kv_mask[b2 * N_ + tt * 64 + i]) m |= (1ull << i);
    mb[t] = m;
  }
}

// ---- main: flash cross-attention, 16x16x32 bf16 MFMA ----
__global__ __launch_bounds__(256, 2) void attn_kernel(
    const float* __restrict__ q, const bf16_t* __restrict__ kp,
    const bf16_t* __restrict__ vt, const unsigned long long* __restrict__ mb,
    float* __restrict__ out) {
  __shared__ __align__(16) bf16_t Qs[QT][PITCH];      // normalized Q (bf16)
  __shared__ __align__(16) bf16_t Ks[NT][PITCH];      // K' tile [n][d]
  __shared__ __align__(16) bf16_t Vs[DH_][PITCH];     // V^T tile [d][n]
  __shared__ __align__(16) bf16_t Ps[4][32][PITCH];   // per-wave P [m][n]

  const int tid  = threadIdx.x;
  const int wave = tid >> 6, lane = tid & 63;
  const int l15  = lane & 15, quad = lane >> 4;
  const int bh   = blockIdx.x >> 3;
  const int m0   = (blockIdx.x & 7) * QT;
  const int b = bh >> 4, h = bh & 15;

  // ---- Q tile: load fp32, silu + L2-normalize over dh, write bf16 to LDS ----
  {
    const int r = tid >> 4, c = tid & 15;
    #pragma unroll
    for (int it = 0; it < QT / 16; ++it) {
      const int row = it * 16 + r;
      float4 v = *(const float4*)(q + ((size_t)(b * M_ + m0 + row)) * D_ + h * DH_ + c * 4);
      float s0 = silu_f(v.x), s1 = silu_f(v.y), s2 = silu_f(v.z), s3 = silu_f(v.w);
      float ss = s0*s0 + s1*s1 + s2*s2 + s3*s3;
      ss += __shfl_xor(ss, 1); ss += __shfl_xor(ss, 2);
      ss += __shfl_xor(ss, 4); ss += __shfl_xor(ss, 8);
      const float inv = 1.0f / fmaxf(sqrtf(ss), 1e-6f);
      union { bf16_t bs[4]; uint2 u; } pk;
      pk.bs[0] = (bf16_t)(s0 * inv); pk.bs[1] = (bf16_t)(s1 * inv);
      pk.bs[2] = (bf16_t)(s2 * inv); pk.bs[3] = (bf16_t)(s3 * inv);
      *(uint2*)&Qs[row][c * 4] = pk.u;
    }
  }
  __syncthreads();

  // Q A-fragments in registers: A[m=lane&15][k=quad*8+j], rows = wave*32 + mt*16 + l15
  bf16x8 qa[2][2];
  #pragma unroll
  for (int mt = 0; mt < 2; ++mt)
    #pragma unroll
    for (int kc = 0; kc < 2; ++kc)
      qa[mt][kc] = *(const bf16x8*)&Qs[wave * 32 + mt * 16 + l15][kc * 32 + quad * 8];

  f32x4 o[2][4];
  float mrun[2][4], lrun[2][4];
  #pragma unroll
  for (int mt = 0; mt < 2; ++mt) {
    #pragma unroll
    for (int jd = 0; jd < 4; ++jd) o[mt][jd] = (f32x4){0.f, 0.f, 0.f, 0.f};
    #pragma unroll
    for (int r = 0; r < 4; ++r) { mrun[mt][r] = -1e30f; lrun[mt][r] = 0.f; }
  }

  const bf16_t* kpb = kp + (size_t)bh * N_ * DH_;
  const bf16_t* vtb = vt + (size_t)bh * DH_ * N_;

  for (int t = 0; t < N_ / NT; ++t) {
    // stage K' [n][d] and V^T [d][n] tiles (coalesced 16B loads -> padded LDS)
    #pragma unroll
    for (int it = 0; it < 2; ++it) {
      const int idx = tid + it * 256;
      const int rr = idx >> 3, c8 = idx & 7;
      *(bf16x8*)&Ks[rr][c8 * 8] = *(const bf16x8*)(kpb + (size_t)(t * NT + rr) * DH_ + c8 * 8);
      *(bf16x8*)&Vs[rr][c8 * 8] = *(const bf16x8*)(vtb + (size_t)rr * N_ + t * NT + c8 * 8);
    }
    __syncthreads();

    const unsigned long long mk = mb[b * (N_ / 64) + t];

    // S = Q' K'^T : C layout row m = quad*4+r (+16*mt), col n = l15 (+16*j)
    f32x4 s[2][4];
    #pragma unroll
    for (int mt = 0; mt < 2; ++mt)
      #pragma unroll
      for (int j = 0; j < 4; ++j) s[mt][j] = (f32x4){0.f, 0.f, 0.f, 0.f};
    #pragma unroll
    for (int kc = 0; kc < 2; ++kc) {
      #pragma unroll
      for (int j = 0; j < 4; ++j) {
        bf16x8 kb = *(const bf16x8*)&Ks[j * 16 + l15][kc * 32 + quad * 8];
        s[0][j] = __builtin_amdgcn_mfma_f32_16x16x32_bf16(qa[0][kc], kb, s[0][j], 0, 0, 0);
        s[1][j] = __builtin_amdgcn_mfma_f32_16x16x32_bf16(qa[1][kc], kb, s[1][j], 0, 0, 0);
      }
    }

    #pragma unroll
    for (int mt = 0; mt < 2; ++mt) {
      float z[4][4];
      #pragma unroll
      for (int j = 0; j < 4; ++j) {
        const bool masked = (mk >> (l15 + 16 * j)) & 1ull;
        #pragma unroll
        for (int r = 0; r < 4; ++r)
          z[j][r] = masked ? -INFINITY : s[mt][j][r] * 0.125f;
      }
      float tmax[4];
      #pragma unroll
      for (int r = 0; r < 4; ++r)
        tmax[r] = fmaxf(fmaxf(z[0][r], z[1][r]), fmaxf(z[2][r], z[3][r]));
      #pragma unroll
      for (int sh = 1; sh < 16; sh <<= 1)
        #pragma unroll
        for (int r = 0; r < 4; ++r)
          tmax[r] = fmaxf(tmax[r], __shfl_xor(tmax[r], sh));
      float al[4];
      #pragma unroll
      for (int r = 0; r < 4; ++r) {
        const float mn = fmaxf(mrun[mt][r], tmax[r]);  // finite always (init -1e30)
        al[r] = __expf(mrun[mt][r] - mn);
        mrun[mt][r] = mn;
      }
      float p[4][4], psum[4];
      #pragma unroll
      for (int r = 0; r < 4; ++r) psum[r] = 0.f;
      #pragma unroll
      for (int j = 0; j < 4; ++j)
        #pragma unroll
        for (int r = 0; r < 4; ++r) {
          p[j][r] = __expf(z[j][r] - mrun[mt][r]);     // exp(-inf - finite) = 0 for masked
          psum[r] += p[j][r];
        }
      #pragma unroll
      for (int sh = 1; sh < 16; sh <<= 1)
        #pragma unroll
        for (int r = 0; r < 4; ++r)
          psum[r] += __shfl_xor(psum[r], sh);
      #pragma unroll
      for (int r = 0; r < 4; ++r)
        lrun[mt][r] = lrun[mt][r] * al[r] + psum[r];
      #pragma unroll
      for (int jd = 0; jd < 4; ++jd)
        #pragma unroll
        for (int r = 0; r < 4; ++r)
          o[mt][jd][r] = o[mt][jd][r] * al[r];
      // P: C layout -> [m][n] LDS (wave-private; same-wave RAW ordered by lgkmcnt)
      #pragma unroll
      for (int j = 0; j < 4; ++j)
        #pragma unroll
        for (int r = 0; r < 4; ++r)
          Ps[wave][mt * 16 + quad * 4 + r][l15 + 16 * j] = (bf16_t)p[j][r];
    }

    // O += P V : A = P[m][k=n] from LDS, B = V^T[d][n] k-contiguous
    #pragma unroll
    for (int kc = 0; kc < 2; ++kc) {
      bf16x8 pa0 = *(const bf16x8*)&Ps[wave][l15][kc * 32 + quad * 8];
      bf16x8 pa1 = *(const bf16x8*)&Ps[wave][16 + l15][kc * 32 + quad * 8];
      #pragma unroll
      for (int jd = 0; jd < 4; ++jd) {
        bf16x8 vb = *(const bf16x8*)&Vs[jd * 16 + l15][kc * 32 + quad * 8];
        o[0][jd] = __builtin_amdgcn_mfma_f32_16x16x32_bf16(pa0, vb, o[0][jd], 0, 0, 0);
        o[1][jd] = __builtin_amdgcn_mfma_f32_16x16x32_bf16(pa1, vb, o[1][jd], 0, 0, 0);
      }
    }
    __syncthreads();  // protect Ks/Vs before next staging
  }

  // epilogue: divide by l, store fp32 (16 lanes x 4B = 64B chunks)
  #pragma unroll
  for (int mt = 0; mt < 2; ++mt)
    #pragma unroll
    for (int r = 0; r < 4; ++r) {
      const float lv = lrun[mt][r];
      const float invl = lv > 0.f ? 1.0f / lv : 0.f;
      const int m = m0 + wave * 32 + mt * 16 + quad * 4 + r;
      const size_t base = ((size_t)(b * M_ + m)) * D_ + h * DH_ + l15;
      #pragma unroll
      for (int jd = 0; jd < 4; ++jd)
        out[base + jd * 16] = o[mt][jd][r] * invl;
    }
}

extern "C" void kernel_launch(void* const* d_in, const int* in_sizes, int n_in,
                              void* d_out, int out_size, void* d_ws, size_t ws_size,
                              hipStream_t stream) {
  const float* q  = (const float*)d_in[0];
  const float* kv = (const float*)d_in[1];
  const int* kv_mask = (const int*)d_in[2];
  float* out = (float*)d_out;

  // ws layout: K' 16MB | Vt 16MB | maskbits 1KB  (total ~33.6MB)
  bf16_t* kp = (bf16_t*)d_ws;
  bf16_t* vt = kp + (size_t)B_ * H_ * N_ * DH_;
  unsigned long long* mb =
      (unsigned long long*)((char*)d_ws + 2 * (size_t)B_ * H_ * N_ * DH_ * sizeof(bf16_t));

  prep_kernel<<<B_ * N_ / 4, 256, 0, stream>>>(kv, kv_mask, kp, vt, mb);
  attn_kernel<<<B_ * H_ * (M_ / QT), 256, 0, stream>>>(q, kp, vt, mb, out);
}

// Round 3
// 168.091 us; speedup vs baseline: 1.4990x; 1.4990x over previous
//
#include <hip/hip_runtime.h>
#include <hip/hip_bf16.h>
#include <cmath>
#include <stdint.h>

#define B_ 4
#define M_ 1024
#define N_ 2048
#define D_ 1024
#define H_ 16
#define DH_ 64
#define QT 128   // Q rows per block (8 waves x 16)
#define NT 64    // N tile
#define PITCH 72 // LDS row pitch in bf16: 144B, 16B-aligned

typedef __bf16 bf16_t;
typedef __attribute__((ext_vector_type(8))) __bf16 bf16x8;
typedef __attribute__((ext_vector_type(4))) float f32x4;

static __device__ __forceinline__ float silu_f(float x) {
  return x / (1.0f + __expf(-x));
}

// ---- prep: K' = L2norm(silu(kv heads)) [bh][n][d]; Vt = kv^T [bh][d][n] via LDS
//      transpose (coalesced both ways); mask bits packed. ----
// grid: b(4) x ntile(32) x headpair(8) = 1024 blocks, 256 threads
__global__ __launch_bounds__(256) void prep_kernel(
    const float* __restrict__ kv, const int* __restrict__ kv_mask,
    bf16_t* __restrict__ kp, bf16_t* __restrict__ vt,
    unsigned long long* __restrict__ mb) {
  __shared__ __align__(16) bf16_t Lt[NT][PITCH];  // V tile [n][d]
  const int bx = blockIdx.x;
  const int hp = bx & 7;
  const int nt = (bx >> 3) & 31;
  const int b  = bx >> 8;
  const int n0 = nt * NT;
  const int tid = threadIdx.x;

  #pragma unroll
  for (int hi = 0; hi < 2; ++hi) {
    const int h = hp * 2 + hi;
    const size_t bh = (size_t)(b * H_ + h);
    // Phase A: load 64x64 fp32 (coalesced 256B/row), silu+norm -> kp; raw -> LDS
    {
      const int r = tid >> 2, c0 = (tid & 3) * 16;
      const float* src = kv + ((size_t)(b * N_ + n0 + r)) * D_ + h * DH_ + c0;
      union { float f[16]; float4 v4[4]; } raw;   // proper type-pun (no UB)
      raw.v4[0] = *(const float4*)(src + 0);
      raw.v4[1] = *(const float4*)(src + 4);
      raw.v4[2] = *(const float4*)(src + 8);
      raw.v4[3] = *(const float4*)(src + 12);
      float sv[16];
      float ss = 0.f;
      #pragma unroll
      for (int i = 0; i < 16; ++i) { sv[i] = silu_f(raw.f[i]); ss += sv[i] * sv[i]; }
      ss += __shfl_xor(ss, 1); ss += __shfl_xor(ss, 2);
      const float inv = 1.0f / fmaxf(sqrtf(ss), 1e-6f);
      union { bf16_t bs[16]; uint4 u[2]; } pk;
      #pragma unroll
      for (int i = 0; i < 16; ++i) pk.bs[i] = (bf16_t)(sv[i] * inv);
      uint4* kdst = (uint4*)(kp + (bh * N_ + n0 + r) * DH_ + c0);
      kdst[0] = pk.u[0]; kdst[1] = pk.u[1];
      // raw V (bf16) into LDS tile [n][d]
      union { bf16_t bs[16]; uint4 u[2]; } pv;
      #pragma unroll
      for (int i = 0; i < 16; ++i) pv.bs[i] = (bf16_t)raw.f[i];
      uint4* ldst = (uint4*)&Lt[r][c0];
      ldst[0] = pv.u[0]; ldst[1] = pv.u[1];
    }
    __syncthreads();
    // Phase B: transposed write vt[bh][d][n] (coalesced 128B per d-row)
    {
      const int d = tid >> 2, nc = (tid & 3) * 16;
      union { bf16_t bs[16]; uint4 u[2]; } pk;
      #pragma unroll
      for (int i = 0; i < 16; ++i) pk.bs[i] = Lt[nc + i][d];
      uint4* dst = (uint4*)(vt + (bh * DH_ + d) * N_ + n0 + nc);
      dst[0] = pk.u[0]; dst[1] = pk.u[1];
    }
    __syncthreads();
  }
  // pack mask bits: word (b,t) bit i <-> kv_mask[b][t*64+i]
  if (bx == 0 && tid < B_ * (N_ / 64)) {
    const int b2 = tid >> 5, tt = tid & 31;
    unsigned long long m = 0ull;
    for (int i = 0; i < 64; ++i)
      if (kv_mask[b2 * N_ + tt * 64 + i]) m |= (1ull << i);
    mb[tid] = m;
  }
}

// ---- main: flash cross-attention, fixed-max softmax, 8 waves x 16 rows ----
__global__ __launch_bounds__(512, 4) void attn_kernel(
    const float* __restrict__ q, const bf16_t* __restrict__ kp,
    const bf16_t* __restrict__ vt, const unsigned long long* __restrict__ mb,
    float* __restrict__ out) {
  __shared__ __align__(16) bf16_t Qs[QT][PITCH];      // normalized Q (bf16)
  __shared__ __align__(16) bf16_t Ks[NT][PITCH];      // K' tile [n][d]
  __shared__ __align__(16) bf16_t Vs[DH_][PITCH];     // V^T tile [d][n]
  __shared__ __align__(16) bf16_t Ps[8][16][PITCH];   // per-wave P [m][n]

  const int tid  = threadIdx.x;
  const int w    = tid >> 6;
  const int lane = tid & 63;
  const int l15  = lane & 15, quad = lane >> 4;
  const int bh   = blockIdx.x >> 3;
  const int m0   = (blockIdx.x & 7) * QT;
  const int b = bh >> 4, h = bh & 15;

  // Q tile: fp32 load, silu + L2-normalize, bf16 -> LDS
  #pragma unroll
  for (int it = 0; it < 4; ++it) {
    const int row = it * 32 + (tid >> 4);
    const int c = tid & 15;
    float4 v = *(const float4*)(q + ((size_t)(b * M_ + m0 + row)) * D_ + h * DH_ + c * 4);
    float s0 = silu_f(v.x), s1 = silu_f(v.y), s2 = silu_f(v.z), s3 = silu_f(v.w);
    float ss = s0*s0 + s1*s1 + s2*s2 + s3*s3;
    ss += __shfl_xor(ss, 1); ss += __shfl_xor(ss, 2);
    ss += __shfl_xor(ss, 4); ss += __shfl_xor(ss, 8);
    const float inv = 1.0f / fmaxf(sqrtf(ss), 1e-6f);
    union { bf16_t bs[4]; uint2 u; } pk;
    pk.bs[0] = (bf16_t)(s0 * inv); pk.bs[1] = (bf16_t)(s1 * inv);
    pk.bs[2] = (bf16_t)(s2 * inv); pk.bs[3] = (bf16_t)(s3 * inv);
    *(uint2*)&Qs[row][c * 4] = pk.u;
  }
  __syncthreads();

  // Q A-fragments: A[m=l15][k=quad*8+j], rows = w*16 + l15
  bf16x8 qa[2];
  #pragma unroll
  for (int kc = 0; kc < 2; ++kc)
    qa[kc] = *(const bf16x8*)&Qs[w * 16 + l15][kc * 32 + quad * 8];

  f32x4 o[4];
  float lrun[4];
  #pragma unroll
  for (int jd = 0; jd < 4; ++jd) o[jd] = (f32x4){0.f, 0.f, 0.f, 0.f};
  #pragma unroll
  for (int r = 0; r < 4; ++r) lrun[r] = 0.f;

  const bf16_t* kpb = kp + (size_t)bh * N_ * DH_;
  const bf16_t* vtb = vt + (size_t)bh * DH_ * N_;

  for (int t = 0; t < N_ / NT; ++t) {
    // stage K'/V^T tiles: 512 threads x one bf16x8 each
    const int rr = tid >> 3, c8 = tid & 7;
    *(bf16x8*)&Ks[rr][c8 * 8] = *(const bf16x8*)(kpb + (size_t)(t * NT + rr) * DH_ + c8 * 8);
    *(bf16x8*)&Vs[rr][c8 * 8] = *(const bf16x8*)(vtb + (size_t)rr * N_ + t * NT + c8 * 8);
    __syncthreads();

    const unsigned long long mk = mb[b * (N_ / 64) + t];

    // S = Q' K'^T : C layout (m=quad*4+r, n=l15+16j)
    f32x4 s[4];
    #pragma unroll
    for (int j = 0; j < 4; ++j) s[j] = (f32x4){0.f, 0.f, 0.f, 0.f};
    #pragma unroll
    for (int kc = 0; kc < 2; ++kc)
      #pragma unroll
      for (int j = 0; j < 4; ++j) {
        bf16x8 kb = *(const bf16x8*)&Ks[j * 16 + l15][kc * 32 + quad * 8];
        s[j] = __builtin_amdgcn_mfma_f32_16x16x32_bf16(qa[kc], kb, s[j], 0, 0, 0);
      }

    // fixed-max softmax: q',k' unit vectors -> |s|<=1 (Cauchy-Schwarz),
    // z = s/8 - 1/8 <= ~0. Exact softmax via constant shift; no running max.
    float p[4][4];
    #pragma unroll
    for (int j = 0; j < 4; ++j) {
      const bool masked = (mk >> (l15 + 16 * j)) & 1ull;
      #pragma unroll
      for (int r = 0; r < 4; ++r) {
        const float e = __expf(s[j][r] * 0.125f - 0.125f);
        p[j][r] = masked ? 0.f : e;
      }
    }
    #pragma unroll
    for (int r = 0; r < 4; ++r)
      lrun[r] += (p[0][r] + p[1][r]) + (p[2][r] + p[3][r]);

    // P: C layout -> [m][n] LDS (wave-private region)
    #pragma unroll
    for (int j = 0; j < 4; ++j)
      #pragma unroll
      for (int r = 0; r < 4; ++r)
        Ps[w][quad * 4 + r][l15 + 16 * j] = (bf16_t)p[j][r];

    // O += P V : A = P[m][k=n] from LDS, B = V^T (k=n contiguous)
    #pragma unroll
    for (int kc = 0; kc < 2; ++kc) {
      bf16x8 pa = *(const bf16x8*)&Ps[w][l15][kc * 32 + quad * 8];
      #pragma unroll
      for (int jd = 0; jd < 4; ++jd) {
        bf16x8 vb = *(const bf16x8*)&Vs[jd * 16 + l15][kc * 32 + quad * 8];
        o[jd] = __builtin_amdgcn_mfma_f32_16x16x32_bf16(pa, vb, o[jd], 0, 0, 0);
      }
    }
    __syncthreads();  // protect Ks/Vs before next staging
  }

  // epilogue: reduce l across the 16 lanes sharing each row, divide, store
  #pragma unroll
  for (int r = 0; r < 4; ++r) {
    lrun[r] += __shfl_xor(lrun[r], 1); lrun[r] += __shfl_xor(lrun[r], 2);
    lrun[r] += __shfl_xor(lrun[r], 4); lrun[r] += __shfl_xor(lrun[r], 8);
  }
  #pragma unroll
  for (int r = 0; r < 4; ++r) {
    const float lv = lrun[r];
    const float invl = lv > 0.f ? 1.0f / lv : 0.f;
    const int m = m0 + w * 16 + quad * 4 + r;
    const size_t base = ((size_t)(b * M_ + m)) * D_ + h * DH_ + l15;
    #pragma unroll
    for (int jd = 0; jd < 4; ++jd)
      out[base + jd * 16] = o[jd][r] * invl;
  }
}

extern "C" void kernel_launch(void* const* d_in, const int* in_sizes, int n_in,
                              void* d_out, int out_size, void* d_ws, size_t ws_size,
                              hipStream_t stream) {
  const float* q  = (const float*)d_in[0];
  const float* kv = (const float*)d_in[1];
  const int* kv_mask = (const int*)d_in[2];
  float* out = (float*)d_out;

  // ws layout: K' 16MB | Vt 16MB | maskbits 1KB
  bf16_t* kp = (bf16_t*)d_ws;
  bf16_t* vt = kp + (size_t)B_ * H_ * N_ * DH_;
  unsigned long long* mb =
      (unsigned long long*)((char*)d_ws + 2 * (size_t)B_ * H_ * N_ * DH_ * sizeof(bf16_t));

  prep_kernel<<<B_ * 32 * 8, 256, 0, stream>>>(kv, kv_mask, kp, vt, mb);
  attn_kernel<<<B_ * H_ * (M_ / QT), 512, 0, stream>>>(q, kp, vt, mb, out);
}